// Round 9
// baseline (238.039 us; speedup 1.0000x reference)
//
#include <hip/hip_runtime.h>

// B=2, C=4, D=64, H=256, W=256. 7-point |Laplacian| MSE between softmax probs
// (classes 1..3) and one-hot targets, mean over all 3*B*D*H*W terms.
//
// R9: TWO-PASS, barrier-free. R5-R8 all pinned at ~3.5 TB/s effective request
// throughput regardless of occupancy/prefetch/swizzle/contiguity -> the
// barrier-coupled plane-march was the wall. Pass 1 streams softmax into a
// packed u32/voxel (3x10b fixed-point probs + 2b target class, 32 MiB in
// d_ws) with zero inter-thread communication. Pass 2 stencils the packed
// array: wave = full w-row, d-march accumulator, w via shfl, h via direct
// re-read of rows h+-1 (cheap at 4 B/voxel, L2/L3-hot), no LDS, no barriers.
// Falls back to the R8 one-pass kernel if ws_size < 32 MiB.

#define CS   (1 << 22)           // per-batch spatial size (d,h,w)
#define NTOT_INV (1.0f / 25165824.0f)
#define BIAS3 ((8 << 20) | (8 << 10) | 8)   // +8 bias per 10-bit one-hot field
#define BAR() asm volatile("s_waitcnt lgkmcnt(0)\n\ts_barrier" ::: "memory")

// ===========================  PASS 1  ====================================
// softmax + pack: u32 = p1[0:10) | p2[10:20) | p3[20:30) | t[30:32)
__device__ __forceinline__ unsigned enc1(float x0, float x1, float x2, float x3,
                                         int t) {
    float m  = fmaxf(fmaxf(x0, x1), fmaxf(x2, x3));
    float e0 = __expf(x0 - m);
    float e1 = __expf(x1 - m);
    float e2 = __expf(x2 - m);
    float e3 = __expf(x3 - m);
    float r  = 1023.f * __builtin_amdgcn_rcpf(e0 + e1 + e2 + e3);
    unsigned p1 = (unsigned)(e1 * r + 0.5f);
    unsigned p2 = (unsigned)(e2 * r + 0.5f);
    unsigned p3 = (unsigned)(e3 * r + 0.5f);
    return p1 | (p2 << 10) | (p3 << 20) | ((unsigned)t << 30);
}

__global__ __launch_bounds__(256) void softmax_pack(
        const float* __restrict__ L,
        const int*   __restrict__ T,
        unsigned*    __restrict__ P) {
    const int t  = blockIdx.x * 256 + threadIdx.x;   // 2,097,152 threads
    const int v  = t << 2;                            // first voxel of quad
    const int b  = v >> 22;
    const int sp = v & (CS - 1);
    const int lidx = ((b << 2) * CS) + sp;
    float4 q0 = *(const float4*)(L + lidx);
    float4 q1 = *(const float4*)(L + lidx + CS);
    float4 q2 = *(const float4*)(L + lidx + 2 * CS);
    float4 q3 = *(const float4*)(L + lidx + 3 * CS);
    int4   qt = *(const int4*)(T + v);
    uint4 o;
    o.x = enc1(q0.x, q1.x, q2.x, q3.x, qt.x);
    o.y = enc1(q0.y, q1.y, q2.y, q3.y, qt.y);
    o.z = enc1(q0.z, q1.z, q2.z, q3.z, qt.z);
    o.w = enc1(q0.w, q1.w, q2.w, q3.w, qt.w);
    *(uint4*)(P + v) = o;
}

// ===========================  PASS 2  ====================================
__device__ __forceinline__ void dec1(unsigned e, float sc, int om,
                                     float& p1, float& p2, float& p3, int& oh) {
    p1 = (float)(e & 1023u) * sc;
    p2 = (float)((e >> 10) & 1023u) * sc;
    p3 = (float)((e >> 20) & 1023u) * sc;
    int tt = (int)(e >> 30);
    oh = ((tt > 0 ? 1 : 0) << (((tt - 1) & 3) * 10)) & om;
}

#define DEC4(E, SC, OM, P1, P2, P3, OH)                                      \
    dec1((E).x, SC, OM, (P1).x, (P2).x, (P3).x, (OH).x);                     \
    dec1((E).y, SC, OM, (P1).y, (P2).y, (P3).y, (OH).y);                     \
    dec1((E).z, SC, OM, (P1).z, (P2).z, (P3).z, (OH).z);                     \
    dec1((E).w, SC, OM, (P1).w, (P2).w, (P3).w, (OH).w);

__global__ __launch_bounds__(256) void stencil_pass(
        const unsigned* __restrict__ P,
        float*          __restrict__ out) {
    const int tid  = threadIdx.x;
    const int lane = tid & 63;        // quad: w = lane*4 .. lane*4+3
    const int wv   = tid >> 6;        // 4 independent waves per block
    int bi = blockIdx.x;              // 1024 = 8(dseg) x 64(h4) x 2(b)
    const int dseg = bi & 7;  bi >>= 3;
    const int h4   = bi & 63; bi >>= 6;
    const int b    = bi;

    const int h   = (h4 << 2) + wv;   // wave's row, 0..255 (all retire)
    const int hu  = (h > 0)   ? h - 1 : 0;
    const int hdn = (h < 255) ? h + 1 : 255;
    const float mc = 1.f / 1023.f;
    const float mu = (h > 0)   ? mc : 0.f;
    const float md = (h < 255) ? mc : 0.f;
    const int   ou = (h > 0)   ? ~0 : 0;
    const int   od = (h < 255) ? ~0 : 0;
    const int d0   = dseg << 3;
    const int baseB = b << 22;
    const int col   = lane << 2;
    const int rowC  = baseB + (h   << 8) + col;
    const int rowU  = baseB + (hu  << 8) + col;
    const int rowD  = baseB + (hdn << 8) + col;

    float4 c1, c2, c3; int4 coh;      // decoded current plane, own row
    float4 a1, a2, a3; int4 aoh;      // running Laplacian accumulator
    float accv = 0.f;

    // seed accumulator with plane d0-1 (zero outside volume)
    {
        const int   dS = (dseg > 0) ? d0 - 1 : 0;
        const float ms = (dseg > 0) ? mc : 0.f;
        const int   os = (dseg > 0) ? ~0 : 0;
        uint4 e = *(const uint4*)(P + rowC + (dS << 16));
        DEC4(e, ms, os, a1, a2, a3, aoh)
        aoh.x += BIAS3; aoh.y += BIAS3; aoh.z += BIAS3; aoh.w += BIAS3;
    }
    // plane d0 -> cur
    {
        uint4 e = *(const uint4*)(P + rowC + (d0 << 16));
        DEC4(e, mc, ~0, c1, c2, c3, coh)
    }
    // prime A-set: n = own row @ d0+1, u/d = neighbor rows @ d0
    uint4 An = *(const uint4*)(P + rowC + (min(d0 + 1, 63) << 16));
    uint4 Au = *(const uint4*)(P + rowU + (d0 << 16));
    uint4 Ad = *(const uint4*)(P + rowD + (d0 << 16));

#pragma unroll
    for (int i = 0; i < 8; ++i) {
        const int d = d0 + i;         // plane being retired this step
        // issue B-set for step i+1 (stays in flight through this step)
        uint4 Bn = make_uint4(0, 0, 0, 0), Bu = Bn, Bd = Bn;
        if (i < 7) {
            Bn = *(const uint4*)(P + rowC + (min(d + 2, 63) << 16));
            Bu = *(const uint4*)(P + rowU + ((d + 1) << 16));
            Bd = *(const uint4*)(P + rowD + ((d + 1) << 16));
        }

        // decode in-plane h-neighbors (masked at h edges)
        float4 u1, u2, u3; int4 uoh;
        float4 v1, v2, v3; int4 voh;
        DEC4(Au, mu, ou, u1, u2, u3, uoh)
        DEC4(Ad, md, od, v1, v2, v3, voh)

        // w-neighbors across quads via shuffle; w=0/255 zero-pad
        float l1 = __shfl_up(c1.w, 1, 64);   float r1 = __shfl_down(c1.x, 1, 64);
        float l2 = __shfl_up(c2.w, 1, 64);   float r2 = __shfl_down(c2.x, 1, 64);
        float l3 = __shfl_up(c3.w, 1, 64);   float r3 = __shfl_down(c3.x, 1, 64);
        int   lo = __shfl_up(coh.w, 1, 64);  int   ro = __shfl_down(coh.x, 1, 64);
        if (lane == 0)  { l1 = l2 = l3 = 0.f; lo = 0; }
        if (lane == 63) { r1 = r2 = r3 = 0.f; ro = 0; }

        a1.x += u1.x + v1.x + l1   + c1.y - 6.f * c1.x;
        a1.y += u1.y + v1.y + c1.x + c1.z - 6.f * c1.y;
        a1.z += u1.z + v1.z + c1.y + c1.w - 6.f * c1.z;
        a1.w += u1.w + v1.w + c1.z + r1   - 6.f * c1.w;
        a2.x += u2.x + v2.x + l2   + c2.y - 6.f * c2.x;
        a2.y += u2.y + v2.y + c2.x + c2.z - 6.f * c2.y;
        a2.z += u2.z + v2.z + c2.y + c2.w - 6.f * c2.z;
        a2.w += u2.w + v2.w + c2.z + r2   - 6.f * c2.w;
        a3.x += u3.x + v3.x + l3   + c3.y - 6.f * c3.x;
        a3.y += u3.y + v3.y + c3.x + c3.z - 6.f * c3.y;
        a3.z += u3.z + v3.z + c3.y + c3.w - 6.f * c3.z;
        a3.w += u3.w + v3.w + c3.z + r3   - 6.f * c3.w;
        aoh.x += uoh.x + voh.x + lo    + coh.y - 6 * coh.x;
        aoh.y += uoh.y + voh.y + coh.x + coh.z - 6 * coh.y;
        aoh.z += uoh.z + voh.z + coh.y + coh.w - 6 * coh.z;
        aoh.w += uoh.w + voh.w + coh.z + ro    - 6 * coh.w;

        // decode next plane (own row @ d+1), masked at the d=63 top
        const float mn = (d + 1 < 64) ? mc : 0.f;
        const int   on = (d + 1 < 64) ? ~0 : 0;
        float4 n1, n2, n3; int4 noh;
        DEC4(An, mn, on, n1, n2, n3, noh)

        // retire plane d
        {
            int t0 = aoh.x + noh.x, t1 = aoh.y + noh.y;
            int t2 = aoh.z + noh.z, t3 = aoh.w + noh.w;
            float lp, lt, df;
            lp = fabsf(a1.x + n1.x); lt = fabsf((float)((t0 & 1023) - 8));          df = lp - lt; accv = fmaf(df, df, accv);
            lp = fabsf(a2.x + n2.x); lt = fabsf((float)(((t0 >> 10) & 1023) - 8));  df = lp - lt; accv = fmaf(df, df, accv);
            lp = fabsf(a3.x + n3.x); lt = fabsf((float)(((t0 >> 20) & 1023) - 8));  df = lp - lt; accv = fmaf(df, df, accv);
            lp = fabsf(a1.y + n1.y); lt = fabsf((float)((t1 & 1023) - 8));          df = lp - lt; accv = fmaf(df, df, accv);
            lp = fabsf(a2.y + n2.y); lt = fabsf((float)(((t1 >> 10) & 1023) - 8));  df = lp - lt; accv = fmaf(df, df, accv);
            lp = fabsf(a3.y + n3.y); lt = fabsf((float)(((t1 >> 20) & 1023) - 8));  df = lp - lt; accv = fmaf(df, df, accv);
            lp = fabsf(a1.z + n1.z); lt = fabsf((float)((t2 & 1023) - 8));          df = lp - lt; accv = fmaf(df, df, accv);
            lp = fabsf(a2.z + n2.z); lt = fabsf((float)(((t2 >> 10) & 1023) - 8));  df = lp - lt; accv = fmaf(df, df, accv);
            lp = fabsf(a3.z + n3.z); lt = fabsf((float)(((t2 >> 20) & 1023) - 8));  df = lp - lt; accv = fmaf(df, df, accv);
            lp = fabsf(a1.w + n1.w); lt = fabsf((float)((t3 & 1023) - 8));          df = lp - lt; accv = fmaf(df, df, accv);
            lp = fabsf(a2.w + n2.w); lt = fabsf((float)(((t3 >> 10) & 1023) - 8));  df = lp - lt; accv = fmaf(df, df, accv);
            lp = fabsf(a3.w + n3.w); lt = fabsf((float)(((t3 >> 20) & 1023) - 8));  df = lp - lt; accv = fmaf(df, df, accv);
        }

        // rotate: cur seeds next accumulator; next becomes cur; B -> A
        a1 = c1; a2 = c2; a3 = c3;
        aoh.x = coh.x + BIAS3; aoh.y = coh.y + BIAS3;
        aoh.z = coh.z + BIAS3; aoh.w = coh.w + BIAS3;
        c1 = n1; c2 = n2; c3 = n3; coh = noh;
        An = Bn; Au = Bu; Ad = Bd;
    }

    // block reduction: wave shuffle -> LDS -> one atomic
    for (int o = 32; o > 0; o >>= 1) accv += __shfl_down(accv, o, 64);
    __shared__ float wsum[4];
    if (lane == 0) wsum[wv] = accv;
    __syncthreads();
    if (tid == 0)
        atomicAdd(out, (wsum[0] + wsum[1] + wsum[2] + wsum[3]) * NTOT_INV);
}

// ====================  FALLBACK: R8 one-pass kernel  ======================
#define ISSUE(S, off)                                                        \
    S##0 = *(const float4*)(L + lBase + (off));                              \
    S##1 = *(const float4*)(L + lBase + (off) + CS);                         \
    S##2 = *(const float4*)(L + lBase + (off) + 2 * CS);                     \
    S##3 = *(const float4*)(L + lBase + (off) + 3 * CS);                     \
    S##t = *(const int4*)(T + tBase + (off));

__device__ __forceinline__ void smax1(float x0, float x1, float x2, float x3,
                                      float vm, float& p1, float& p2, float& p3) {
    float m  = fmaxf(fmaxf(x0, x1), fmaxf(x2, x3));
    float e0 = __expf(x0 - m);
    float e1 = __expf(x1 - m);
    float e2 = __expf(x2 - m);
    float e3 = __expf(x3 - m);
    float r  = vm * __builtin_amdgcn_rcpf(e0 + e1 + e2 + e3);
    p1 = e1 * r; p2 = e2 * r; p3 = e3 * r;
}

__device__ __forceinline__ int ohenc(int t, int msk) {
    int nz = (t > 0) ? 1 : 0;
    return (nz << (((t - 1) & 3) * 10)) & msk;
}

__global__ __launch_bounds__(512) void boundary_loss_kernel(
        const float* __restrict__ L,
        const int*   __restrict__ T,
        float*       __restrict__ out) {
    const int tid  = threadIdx.x;
    const int lane = tid & 63;
    const int th   = tid >> 6;
    int bi = blockIdx.x;
    const int dseg = bi & 7;  bi >>= 3;
    const int ht   = bi % 43;
    const int b    = bi / 43;

    const int   h   = ht * 6 + th - 1;
    const bool  hv  = ((unsigned)h < 256u);
    const int   hcl = min(max(h, 0), 255);
    const float vm  = hv ? 1.f : 0.f;
    const int   ohm = hv ? ~0 : 0;
    const bool  live = (th >= 1) && (th <= 6) && hv;
    const int   d0  = dseg << 3;

    const int rowoff = (hcl << 8) + (lane << 2);
    const int tBase  = b * CS + rowoff;
    const int lBase  = (b << 2) * CS + rowoff;

    __shared__ float P1[8][256], P2[8][256], P3[8][256];
    __shared__ int   OH[8][256];
    const int c0 = lane << 2;

    float4 c1, c2, c3; int4 coh;
    float4 a1, a2, a3; int4 aoh;
    float accv = 0.f;

    {
        const int   off  = (dseg > 0 ? d0 - 1 : 0) << 16;
        const float svm  = (dseg > 0) ? vm : 0.f;
        const int   sohm = (dseg > 0) ? ohm : 0;
        float4 q0, q1, q2, q3; int4 qt;
        ISSUE(q, off)
        smax1(q0.x, q1.x, q2.x, q3.x, svm, a1.x, a2.x, a3.x);
        smax1(q0.y, q1.y, q2.y, q3.y, svm, a1.y, a2.y, a3.y);
        smax1(q0.z, q1.z, q2.z, q3.z, svm, a1.z, a2.z, a3.z);
        smax1(q0.w, q1.w, q2.w, q3.w, svm, a1.w, a2.w, a3.w);
        aoh.x = ohenc(qt.x, sohm) + BIAS3; aoh.y = ohenc(qt.y, sohm) + BIAS3;
        aoh.z = ohenc(qt.z, sohm) + BIAS3; aoh.w = ohenc(qt.w, sohm) + BIAS3;
    }
    {
        const int off = d0 << 16;
        float4 q0, q1, q2, q3; int4 qt;
        ISSUE(q, off)
        smax1(q0.x, q1.x, q2.x, q3.x, vm, c1.x, c2.x, c3.x);
        smax1(q0.y, q1.y, q2.y, q3.y, vm, c1.y, c2.y, c3.y);
        smax1(q0.z, q1.z, q2.z, q3.z, vm, c1.z, c2.z, c3.z);
        smax1(q0.w, q1.w, q2.w, q3.w, vm, c1.w, c2.w, c3.w);
        coh.x = ohenc(qt.x, ohm); coh.y = ohenc(qt.y, ohm);
        coh.z = ohenc(qt.z, ohm); coh.w = ohenc(qt.w, ohm);
    }
    float4 A0, A1, A2, A3; int4 At;
    {
        const int off = (d0 + 1 < 64 ? d0 + 1 : 63) << 16;
        ISSUE(A, off)
    }
#pragma unroll
    for (int i = 0; i < 8; ++i) {
        float4 B0, B1, B2, B3; int4 Bt;
        B0 = B1 = B2 = B3 = make_float4(0.f, 0.f, 0.f, 0.f);
        Bt = make_int4(0, 0, 0, 0);
        if (i < 7) {
            const int off = (d0 + i + 2 < 64 ? d0 + i + 2 : 63) << 16;
            ISSUE(B, off)
        }
        BAR();
        *(float4*)&P1[th][c0] = c1;
        *(float4*)&P2[th][c0] = c2;
        *(float4*)&P3[th][c0] = c3;
        *(int4*)&OH[th][c0]   = coh;
        BAR();
        if (live) {
            float l1 = __shfl_up(c1.w, 1, 64);   float r1 = __shfl_down(c1.x, 1, 64);
            float l2 = __shfl_up(c2.w, 1, 64);   float r2 = __shfl_down(c2.x, 1, 64);
            float l3 = __shfl_up(c3.w, 1, 64);   float r3 = __shfl_down(c3.x, 1, 64);
            int   lo = __shfl_up(coh.w, 1, 64);  int   ro = __shfl_down(coh.x, 1, 64);
            if (lane == 0)  { l1 = l2 = l3 = 0.f; lo = 0; }
            if (lane == 63) { r1 = r2 = r3 = 0.f; ro = 0; }
            float4 u, v;
            u = *(float4*)&P1[th - 1][c0]; v = *(float4*)&P1[th + 1][c0];
            a1.x += u.x + v.x + l1   + c1.y - 6.f * c1.x;
            a1.y += u.y + v.y + c1.x + c1.z - 6.f * c1.y;
            a1.z += u.z + v.z + c1.y + c1.w - 6.f * c1.z;
            a1.w += u.w + v.w + c1.z + r1   - 6.f * c1.w;
            u = *(float4*)&P2[th - 1][c0]; v = *(float4*)&P2[th + 1][c0];
            a2.x += u.x + v.x + l2   + c2.y - 6.f * c2.x;
            a2.y += u.y + v.y + c2.x + c2.z - 6.f * c2.y;
            a2.z += u.z + v.z + c2.y + c2.w - 6.f * c2.z;
            a2.w += u.w + v.w + c2.z + r2   - 6.f * c2.w;
            u = *(float4*)&P3[th - 1][c0]; v = *(float4*)&P3[th + 1][c0];
            a3.x += u.x + v.x + l3   + c3.y - 6.f * c3.x;
            a3.y += u.y + v.y + c3.x + c3.z - 6.f * c3.y;
            a3.z += u.z + v.z + c3.y + c3.w - 6.f * c3.z;
            a3.w += u.w + v.w + c3.z + r3   - 6.f * c3.w;
            int4 iu = *(int4*)&OH[th - 1][c0];
            int4 id = *(int4*)&OH[th + 1][c0];
            aoh.x += iu.x + id.x + lo    + coh.y - 6 * coh.x;
            aoh.y += iu.y + id.y + coh.x + coh.z - 6 * coh.y;
            aoh.z += iu.z + id.z + coh.y + coh.w - 6 * coh.z;
            aoh.w += iu.w + id.w + coh.z + ro    - 6 * coh.w;
        }
        const int   dnA  = d0 + i + 1;
        const float vmn  = (dnA < 64) ? vm : 0.f;
        const int   ohmn = (dnA < 64) ? ohm : 0;
        float4 n1, n2, n3; int4 noh;
        smax1(A0.x, A1.x, A2.x, A3.x, vmn, n1.x, n2.x, n3.x);
        smax1(A0.y, A1.y, A2.y, A3.y, vmn, n1.y, n2.y, n3.y);
        smax1(A0.z, A1.z, A2.z, A3.z, vmn, n1.z, n2.z, n3.z);
        smax1(A0.w, A1.w, A2.w, A3.w, vmn, n1.w, n2.w, n3.w);
        noh.x = ohenc(At.x, ohmn); noh.y = ohenc(At.y, ohmn);
        noh.z = ohenc(At.z, ohmn); noh.w = ohenc(At.w, ohmn);
        if (live) {
            int t0 = aoh.x + noh.x, t1 = aoh.y + noh.y;
            int t2 = aoh.z + noh.z, t3 = aoh.w + noh.w;
            float lp, lt, df;
            lp = fabsf(a1.x + n1.x); lt = fabsf((float)((t0 & 1023) - 8));          df = lp - lt; accv = fmaf(df, df, accv);
            lp = fabsf(a2.x + n2.x); lt = fabsf((float)(((t0 >> 10) & 1023) - 8));  df = lp - lt; accv = fmaf(df, df, accv);
            lp = fabsf(a3.x + n3.x); lt = fabsf((float)(((t0 >> 20) & 1023) - 8));  df = lp - lt; accv = fmaf(df, df, accv);
            lp = fabsf(a1.y + n1.y); lt = fabsf((float)((t1 & 1023) - 8));          df = lp - lt; accv = fmaf(df, df, accv);
            lp = fabsf(a2.y + n2.y); lt = fabsf((float)(((t1 >> 10) & 1023) - 8));  df = lp - lt; accv = fmaf(df, df, accv);
            lp = fabsf(a3.y + n3.y); lt = fabsf((float)(((t1 >> 20) & 1023) - 8));  df = lp - lt; accv = fmaf(df, df, accv);
            lp = fabsf(a1.z + n1.z); lt = fabsf((float)((t2 & 1023) - 8));          df = lp - lt; accv = fmaf(df, df, accv);
            lp = fabsf(a2.z + n2.z); lt = fabsf((float)(((t2 >> 10) & 1023) - 8));  df = lp - lt; accv = fmaf(df, df, accv);
            lp = fabsf(a3.z + n3.z); lt = fabsf((float)(((t2 >> 20) & 1023) - 8));  df = lp - lt; accv = fmaf(df, df, accv);
            lp = fabsf(a1.w + n1.w); lt = fabsf((float)((t3 & 1023) - 8));          df = lp - lt; accv = fmaf(df, df, accv);
            lp = fabsf(a2.w + n2.w); lt = fabsf((float)(((t3 >> 10) & 1023) - 8));  df = lp - lt; accv = fmaf(df, df, accv);
            lp = fabsf(a3.w + n3.w); lt = fabsf((float)(((t3 >> 20) & 1023) - 8));  df = lp - lt; accv = fmaf(df, df, accv);
        }
        a1 = c1; a2 = c2; a3 = c3;
        aoh.x = coh.x + BIAS3; aoh.y = coh.y + BIAS3;
        aoh.z = coh.z + BIAS3; aoh.w = coh.w + BIAS3;
        c1 = n1; c2 = n2; c3 = n3; coh = noh;
        A0 = B0; A1 = B1; A2 = B2; A3 = B3; At = Bt;
    }
    for (int o = 32; o > 0; o >>= 1) accv += __shfl_down(accv, o, 64);
    __shared__ float wsum[8];
    if (lane == 0) wsum[th] = accv;
    __syncthreads();
    if (tid == 0) {
        float s = wsum[0] + wsum[1] + wsum[2] + wsum[3]
                + wsum[4] + wsum[5] + wsum[6] + wsum[7];
        atomicAdd(out, s * NTOT_INV);
    }
}

extern "C" void kernel_launch(void* const* d_in, const int* in_sizes, int n_in,
                              void* d_out, int out_size, void* d_ws, size_t ws_size,
                              hipStream_t stream) {
    const float* logits  = (const float*)d_in[0];
    const int*   targets = (const int*)d_in[1];
    float*       out     = (float*)d_out;

    hipMemsetAsync(out, 0, sizeof(float), stream);   // d_out is poisoned 0xAA

    if (ws_size >= (size_t)(1u << 25)) {             // need 32 MiB of scratch
        unsigned* P = (unsigned*)d_ws;
        softmax_pack<<<8192, 256, 0, stream>>>(logits, targets, P);
        stencil_pass<<<1024, 256, 0, stream>>>(P, out);
    } else {
        boundary_loss_kernel<<<688, 512, 0, stream>>>(logits, targets, out);
    }
}